// Round 10
// baseline (144.221 us; speedup 1.0000x reference)
//
#include <hip/hip_runtime.h>
#include <type_traits>

#define NUM_CATEGORIES 64
#define IN_DIM 1024
#define OUT_DIM 1024
#define BATCH 32
#define SEQ 512

#define BM 256
#define BN 256
#define BK 32
#define NSTEP (IN_DIM / BK)   // 32

#define LDBW 260   // u32 words per B k-pair row (256 data + 4 pad)

typedef float f32x4 __attribute__((ext_vector_type(4)));
typedef float f32x2 __attribute__((ext_vector_type(2)));
typedef unsigned int u32x4 __attribute__((ext_vector_type(4)));
typedef __bf16 bf16x2 __attribute__((ext_vector_type(2)));
typedef __bf16 bf16x4 __attribute__((ext_vector_type(4)));
typedef __bf16 bf16x8 __attribute__((ext_vector_type(8)));

__global__ __launch_bounds__(512, 2)
void cslinear_kernel(const float* __restrict__ x,
                     const int* __restrict__ cid,
                     const float* __restrict__ weight,
                     const float* __restrict__ bias,
                     float* __restrict__ out) {
    // LDS holds ONLY B (A-fragments are lane-row-contiguous in global x and
    // come straight from L1 — no transpose needed, so no LDS staging for A).
    __shared__ unsigned int Bs[2][(BK / 2) * LDBW];   // 2 x 16.25 KB

    const int t    = threadIdx.x;
    const int lane = t & 63;
    const int w    = t >> 6;      // 0..7

    // XCD-aware remap: slot s -> XCD s%8; each XCD owns 4 whole batches.
    const int s    = blockIdx.x;      // 0..255
    const int xcd  = s & 7;
    const int ixd  = s >> 3;          // 0..31
    const int b    = xcd + 8 * (ixd >> 3);
    const int j    = ixd & 7;
    const int nt   = j & 3;           // 0..3
    const int mt   = j >> 2;          // 0..1

    const int c = cid[b];
    const float* Wp = weight + (size_t)c * IN_DIM * OUT_DIM + (size_t)nt * BN;
    const float* Xp = x + ((size_t)b * SEQ + (size_t)mt * BM) * IN_DIM;
    float* Op = out + ((size_t)b * SEQ + (size_t)mt * BM) * OUT_DIM + (size_t)nt * BN;

    f32x4 acc[8][4] = {};               // wave tile 128(m) x 64(n)

    const int mbase = (w >> 2) * 128;
    const int nbase = (w & 3) * 64;
    const int lrow  = lane & 15;
    const int lhi   = lane >> 4;

    // per-lane A base: row (mbase+lrow), k-offset lhi*8
    const float* Abase = Xp + (size_t)(mbase + lrow) * IN_DIM + lhi * 8;

    // 2-deep B staging sets (static indices only — rule #20)
    f32x4 rb0[2][2], rb1[2][2];

    auto LOADB = [&](int ks, auto S) {
        constexpr int ss = decltype(S)::value;
        const float* Wk = Wp + (size_t)(ks * BK) * OUT_DIM;
        #pragma unroll
        for (int i = 0; i < 2; ++i) {
            int u  = i * 512 + t;
            int kp = u >> 6;
            int n4 = u & 63;
            const float* bse = Wk + (size_t)(2 * kp) * OUT_DIM + n4 * 4;
            rb0[ss][i] = *reinterpret_cast<const f32x4*>(bse);
            rb1[ss][i] = *reinterpret_cast<const f32x4*>(bse + OUT_DIM);
        }
    };

    auto STOREB = [&](auto S) {
        constexpr int ss = decltype(S)::value;
        unsigned int* BsW = &Bs[ss][0];
        #pragma unroll
        for (int i = 0; i < 2; ++i) {
            int u  = i * 512 + t;
            int kp = u >> 6;
            int n4 = u & 63;
            u32x4 q;
            #pragma unroll
            for (int jj = 0; jj < 4; ++jj) {
                f32x2 pr;
                pr.x = rb0[ss][i][jj];   // k   (low 16)
                pr.y = rb1[ss][i][jj];   // k+1 (high 16)
                bf16x2 pb = __builtin_convertvector(pr, bf16x2);
                q[jj] = __builtin_bit_cast(unsigned int, pb);
            }
            *reinterpret_cast<u32x4*>(BsW + kp * LDBW + n4 * 4) = q;
        }
    };

    auto COMPUTE = [&](int ks, auto S) {
        constexpr int ss = decltype(S)::value;
        const unsigned int* BsW = &Bs[ss][0];
        // B frags from LDS (u32 k-pair words ARE the bf16x8 layout)
        bf16x8 bfr[4];
        #pragma unroll
        for (int ni = 0; ni < 4; ++ni) {
            int n   = nbase + ni * 16 + lrow;
            int kp0 = lhi * 4;
            u32x4 wds;
            #pragma unroll
            for (int jj = 0; jj < 4; ++jj)
                wds[jj] = BsW[(kp0 + jj) * LDBW + n];
            bfr[ni] = __builtin_bit_cast(bf16x8, wds);
        }
        // A frags straight from global (L1-resident panel), convert in-reg
        const float* Ak = Abase + ks * BK;
        #pragma unroll
        for (int mi = 0; mi < 8; ++mi) {
            const float* ap = Ak + (size_t)(mi * 16) * IN_DIM;
            f32x4 a0 = *reinterpret_cast<const f32x4*>(ap);
            f32x4 a1 = *reinterpret_cast<const f32x4*>(ap + 4);
            bf16x4 lo = __builtin_convertvector(a0, bf16x4);
            bf16x4 hi = __builtin_convertvector(a1, bf16x4);
            bf16x8 afr;
            #pragma unroll
            for (int e = 0; e < 4; ++e) { afr[e] = lo[e]; afr[e + 4] = hi[e]; }
            #pragma unroll
            for (int ni = 0; ni < 4; ++ni)
                acc[mi][ni] = __builtin_amdgcn_mfma_f32_16x16x32_bf16(
                    afr, bfr[ni], acc[mi][ni], 0, 0, 0);
        }
    };

    constexpr std::integral_constant<int, 0> S0{};
    constexpr std::integral_constant<int, 1> S1{};

    // prologue: tile0 -> buf0; tile1 B-loads in flight
    LOADB(0, S0);
    STOREB(S0);
    LOADB(1, S1);
    asm volatile("s_waitcnt lgkmcnt(0)" ::: "memory");
    __builtin_amdgcn_s_barrier();

    // one barrier region per K-step: COMPUTE(p) ∥ STOREB(p^1) ∥ LOADB issue.
    // lgkmcnt(0) before each barrier drains this region's ds_reads of buf p
    // and ds_writes of buf p^1, so next region's writes to p are safe.
    for (int ks = 0; ks < NSTEP; ks += 2) {
        COMPUTE(ks, S0);
        STOREB(S1);                               // vmcnt-counted (1 step old)
        if (ks + 2 < NSTEP) LOADB(ks + 2, S0);
        asm volatile("s_waitcnt lgkmcnt(0)" ::: "memory");
        __builtin_amdgcn_s_barrier();

        COMPUTE(ks + 1, S1);
        if (ks + 2 < NSTEP) STOREB(S0);
        if (ks + 3 < NSTEP) LOADB(ks + 3, S1);
        if (ks + 2 < NSTEP) {
            asm volatile("s_waitcnt lgkmcnt(0)" ::: "memory");
            __builtin_amdgcn_s_barrier();
        }
    }

    // epilogue: C/D layout col=lane&15, row=(lane>>4)*4+reg
    const int lcol  = lane & 15;
    const int lrow4 = (lane >> 4) * 4;
    float bv[4];
    #pragma unroll
    for (int ni = 0; ni < 4; ++ni)
        bv[ni] = bias[(size_t)c * OUT_DIM + nt * BN + nbase + ni * 16 + lcol];

    #pragma unroll
    for (int mi = 0; mi < 8; ++mi) {
        int rbase = mbase + mi * 16 + lrow4;
        #pragma unroll
        for (int ni = 0; ni < 4; ++ni) {
            int ncol = nbase + ni * 16 + lcol;
            #pragma unroll
            for (int r = 0; r < 4; ++r) {
                Op[(size_t)(rbase + r) * OUT_DIM + ncol] = acc[mi][ni][r] + bv[ni];
            }
        }
    }
}

extern "C" void kernel_launch(void* const* d_in, const int* in_sizes, int n_in,
                              void* d_out, int out_size, void* d_ws, size_t ws_size,
                              hipStream_t stream) {
    const float* x      = (const float*)d_in[0];
    const int*   cid    = (const int*)d_in[1];
    const float* weight = (const float*)d_in[2];
    const float* bias   = (const float*)d_in[3];
    float* out = (float*)d_out;

    dim3 grid(256);     // flat: XCD-aware remap inside kernel; 1 block/CU
    dim3 block(512);
    hipLaunchKernelGGL(cslinear_kernel, grid, block, 0, stream,
                       x, cid, weight, bias, out);
}

// Round 11
// 53.421 us; speedup vs baseline: 2.6997x; 2.6997x over previous
//
#include <hip/hip_runtime.h>
#include <type_traits>

#define NUM_CATEGORIES 64
#define IN_DIM 1024
#define OUT_DIM 1024
#define BATCH 32
#define SEQ 512

#define BM 256
#define BN 256
#define BK 32
#define NSTEP (IN_DIM / BK)   // 32

#define LDA 40     // bf16 elems per A row (64B data + 16B pad)
#define LDBW 260   // u32 words per B k-pair row (256 data + 4 pad)

typedef float f32x4 __attribute__((ext_vector_type(4)));
typedef float f32x2 __attribute__((ext_vector_type(2)));
typedef unsigned int u32x4 __attribute__((ext_vector_type(4)));
typedef __bf16 bf16x2 __attribute__((ext_vector_type(2)));
typedef __bf16 bf16x4 __attribute__((ext_vector_type(4)));
typedef __bf16 bf16x8 __attribute__((ext_vector_type(8)));

__global__ __launch_bounds__(512, 2)
void cslinear_kernel(const float* __restrict__ x,
                     const int* __restrict__ cid,
                     const float* __restrict__ weight,
                     const float* __restrict__ bias,
                     float* __restrict__ out) {
    __shared__ unsigned short As[2][BM * LDA];          // 2 x 20 KB
    __shared__ unsigned int   Bs[2][(BK / 2) * LDBW];   // 2 x 16.25 KB

    const int t    = threadIdx.x;
    const int lane = t & 63;
    const int w    = t >> 6;      // 0..7

    // XCD-aware remap: slot s -> XCD s%8; each XCD owns 4 whole batches.
    const int s    = blockIdx.x;      // 0..255
    const int xcd  = s & 7;
    const int ixd  = s >> 3;          // 0..31
    const int b    = xcd + 8 * (ixd >> 3);
    const int j    = ixd & 7;
    const int nt   = j & 3;           // 0..3
    const int mt   = j >> 2;          // 0..1

    const int c = cid[b];
    const float* Wp = weight + (size_t)c * IN_DIM * OUT_DIM + (size_t)nt * BN;
    const float* Xp = x + ((size_t)b * SEQ + (size_t)mt * BM) * IN_DIM;
    float* Op = out + ((size_t)b * SEQ + (size_t)mt * BM) * OUT_DIM + (size_t)nt * BN;

    f32x4 acc[8][4] = {};               // wave tile 128(m) x 64(n)

    const int mbase = (w >> 2) * 128;
    const int nbase = (w & 3) * 64;
    const int lrow  = lane & 15;
    const int lhi   = lane >> 4;

    // 2-deep staging sets, ALL indices compile-time (rule #20)
    f32x4 ra[2][4];
    f32x4 rb0[2][2], rb1[2][2];

    auto LOAD_A = [&](int ks, auto S) {
        constexpr int ss = decltype(S)::value;
        const float* Xk = Xp + ks * BK;
        #pragma unroll
        for (int i = 0; i < 4; ++i) {
            int f   = i * 512 + t;
            int row = f >> 3;
            int c4  = f & 7;
            ra[ss][i] = *reinterpret_cast<const f32x4*>(Xk + (size_t)row * IN_DIM + c4 * 4);
        }
    };
    auto LOAD_B = [&](int ks, auto S) {
        constexpr int ss = decltype(S)::value;
        const float* Wk = Wp + (size_t)(ks * BK) * OUT_DIM;
        #pragma unroll
        for (int i = 0; i < 2; ++i) {
            int u  = i * 512 + t;
            int kp = u >> 6;
            int n4 = u & 63;
            const float* bse = Wk + (size_t)(2 * kp) * OUT_DIM + n4 * 4;
            rb0[ss][i] = *reinterpret_cast<const f32x4*>(bse);
            rb1[ss][i] = *reinterpret_cast<const f32x4*>(bse + OUT_DIM);
        }
    };

    // staging pieces (v_cvt_pk_bf16_f32 via native casts)
    auto ST_A = [&](auto S, auto I) {   // one A ds_write (i = I)
        constexpr int ss = decltype(S)::value;
        constexpr int i  = decltype(I)::value;
        char* AsB = reinterpret_cast<char*>(&As[ss][0]);
        int f   = i * 512 + t;
        int row = f >> 3;
        int c4  = f & 7;
        bf16x4 a4 = __builtin_convertvector(ra[ss][i], bf16x4);
        *reinterpret_cast<bf16x4*>(AsB + row * (LDA * 2) + c4 * 8) = a4;
    };
    auto ST_B = [&](auto S, auto I) {   // one B ds_write (i = I)
        constexpr int ss = decltype(S)::value;
        constexpr int i  = decltype(I)::value;
        unsigned int* BsW = &Bs[ss][0];
        int u  = i * 512 + t;
        int kp = u >> 6;
        int n4 = u & 63;
        u32x4 q;
        #pragma unroll
        for (int jj = 0; jj < 4; ++jj) {
            f32x2 pr;
            pr.x = rb0[ss][i][jj];
            pr.y = rb1[ss][i][jj];
            bf16x2 pb = __builtin_convertvector(pr, bf16x2);
            q[jj] = __builtin_bit_cast(unsigned int, pb);
        }
        *reinterpret_cast<u32x4*>(BsW + kp * LDBW + n4 * 4) = q;
    };

    constexpr std::integral_constant<int, 0> I0{};
    constexpr std::integral_constant<int, 1> I1{};
    constexpr std::integral_constant<int, 2> I2{};
    constexpr std::integral_constant<int, 3> I3{};
    constexpr std::integral_constant<int, 0> S0{};
    constexpr std::integral_constant<int, 1> S1{};

    // one MFMA cluster: A-frag pair (mi=q*2, q*2+1) + 8 MFMA, setprio-wrapped
    auto CLUSTER = [&](auto S, auto Q, const bf16x8* bfr) {
        constexpr int ss = decltype(S)::value;
        constexpr int q  = decltype(Q)::value;
        const char* AsB = reinterpret_cast<const char*>(&As[ss][0]);
        __builtin_amdgcn_s_setprio(1);
        #pragma unroll
        for (int mi = q * 2; mi < q * 2 + 2; ++mi) {
            int r = mbase + mi * 16 + lrow;
            bf16x8 afr = *reinterpret_cast<const bf16x8*>(AsB + r * (LDA * 2) + lhi * 16);
            #pragma unroll
            for (int ni = 0; ni < 4; ++ni)
                acc[mi][ni] = __builtin_amdgcn_mfma_f32_16x16x32_bf16(
                    afr, bfr[ni], acc[mi][ni], 0, 0, 0);
        }
        __builtin_amdgcn_s_setprio(0);
    };

    // region: compute buf Sc; stage set Sn -> buf Sn; issue loads ksl -> set Sc
    auto REGION = [&](auto Sc, auto Sn, bool do_store, bool do_load, int ksl) {
        constexpr int sc = decltype(Sc)::value;
        const unsigned int* BsW = &Bs[sc][0];
        // B frags up front (16 x b32; 2-lane/bank = free)
        bf16x8 bfr[4];
        #pragma unroll
        for (int ni = 0; ni < 4; ++ni) {
            int n   = nbase + ni * 16 + lrow;
            int kp0 = lhi * 4;
            u32x4 wds;
            #pragma unroll
            for (int jj = 0; jj < 4; ++jj)
                wds[jj] = BsW[(kp0 + jj) * LDBW + n];
            bfr[ni] = __builtin_bit_cast(bf16x8, wds);
        }
        // 4 clusters, each followed by one staging piece / load half
        CLUSTER(Sc, I0, bfr);
        if (do_store) { ST_A(Sn, I0); ST_A(Sn, I1); }
        CLUSTER(Sc, I1, bfr);
        if (do_store) { ST_A(Sn, I2); ST_A(Sn, I3); }
        if (do_load)  LOAD_A(ksl, Sc);
        CLUSTER(Sc, I2, bfr);
        if (do_store) { ST_B(Sn, I0); }
        CLUSTER(Sc, I3, bfr);
        if (do_store) { ST_B(Sn, I1); }
        if (do_load)  LOAD_B(ksl, Sc);
    };

    // prologue: tile0 -> buf0; tile1 loads in flight
    LOAD_A(0, S0); LOAD_B(0, S0);
    ST_A(S0, I0); ST_A(S0, I1); ST_A(S0, I2); ST_A(S0, I3);
    ST_B(S0, I0); ST_B(S0, I1);
    LOAD_A(1, S1); LOAD_B(1, S1);
    asm volatile("s_waitcnt lgkmcnt(0)" ::: "memory");
    __builtin_amdgcn_s_barrier();

    // Safety: single lgkmcnt(0) before each barrier drains this region's
    // ds_reads of buf p AND ds_writes of buf p^1, so the next region's writes
    // to buf p are ordered after all reads of buf p.
    for (int ks = 0; ks < NSTEP; ks += 2) {
        REGION(S0, S1, true, ks + 2 < NSTEP, ks + 2);
        asm volatile("s_waitcnt lgkmcnt(0)" ::: "memory");
        __builtin_amdgcn_s_barrier();

        REGION(S1, S0, ks + 2 < NSTEP, ks + 3 < NSTEP, ks + 3);
        if (ks + 2 < NSTEP) {
            asm volatile("s_waitcnt lgkmcnt(0)" ::: "memory");
            __builtin_amdgcn_s_barrier();
        }
    }

    // epilogue: C/D layout col=lane&15, row=(lane>>4)*4+reg
    const int lcol  = lane & 15;
    const int lrow4 = (lane >> 4) * 4;
    float bv[4];
    #pragma unroll
    for (int ni = 0; ni < 4; ++ni)
        bv[ni] = bias[(size_t)c * OUT_DIM + nt * BN + nbase + ni * 16 + lcol];

    #pragma unroll
    for (int mi = 0; mi < 8; ++mi) {
        int rbase = mbase + mi * 16 + lrow4;
        #pragma unroll
        for (int ni = 0; ni < 4; ++ni) {
            int ncol = nbase + ni * 16 + lcol;
            #pragma unroll
            for (int r = 0; r < 4; ++r) {
                Op[(size_t)(rbase + r) * OUT_DIM + ncol] = acc[mi][ni][r] + bv[ni];
            }
        }
    }
}

extern "C" void kernel_launch(void* const* d_in, const int* in_sizes, int n_in,
                              void* d_out, int out_size, void* d_ws, size_t ws_size,
                              hipStream_t stream) {
    const float* x      = (const float*)d_in[0];
    const int*   cid    = (const int*)d_in[1];
    const float* weight = (const float*)d_in[2];
    const float* bias   = (const float*)d_in[3];
    float* out = (float*)d_out;

    dim3 grid(256);     // flat: XCD-aware remap inside kernel; 1 block/CU
    dim3 block(512);
    hipLaunchKernelGGL(cslinear_kernel, grid, block, 0, stream,
                       x, cid, weight, bias, out);
}